// Round 4
// baseline (455.313 us; speedup 1.0000x reference)
//
#include <hip/hip_runtime.h>

typedef float __attribute__((ext_vector_type(4))) f32x4;

// OUT[n, c=j*8+k, h, w] = sum_{a,m,b} W[j,a,m,b,k] * T[n,(j+a-1)*4+m, (h-1)%28, (w+b-2)%28]
//   T[n,cc,h,w] = x[n,cc,h,w] + x[n,cc+128,h,w]
//   (j+a-1) outside [0,32) -> zero (channel pad); (w+b-1) outside [0,28) -> zero (w pad)
//
// R4: DMA-double-buffered row pipeline, raw barriers + counted vmcnt (T3/T4 minimal form).
//   grid = 768 (3 blocks/CU at 48 KB LDS), strips of 5 rows (first 512) / 4 rows (last 256)
//   over the global row index R = n*28 + h.
// Per row r: vmcnt(7) [drain row r's 8 DMAs; prev row's 7 stores may fly] -> s_barrier ->
//   reduce raw->sum -> lgkmcnt(0)+s_barrier -> issue DMA for row r+1 into raw ->
//   compute row r from sum + store. HBM latency hides under the 1008-FMA compute.
// NO registers held across compute (R3 spilled 620 MB of scratch doing that).
// LDS layout (R2-verified, 0 bank conflicts): [ch][32] quads, qpos = q ^ ((ch>>2)&7);
//   swizzle applied to the GLOBAL source address (DMA dest must be linear).

__global__ __launch_bounds__(256, 3) void fused_shift_conv(
    const float* __restrict__ x, const float* __restrict__ Wt, float* __restrict__ out)
{
    __shared__ __align__(16) float raw[8192];   // [half][ch][32] quad-swizzled, 32 KB
    __shared__ __align__(16) float sum[4096];   // [ch][32] reduced, 16 KB

    const int b     = blockIdx.x;
    const int nrows = (b < 512) ? 5 : 4;
    const int row0  = b * 4 + (b < 512 ? b : 512);   // global row index n*28+h

    const int t    = threadIdx.x;
    const int lane = t & 63;
    const int wv   = t >> 6;

    // ---- row-invariant DMA source offsets (within one (n,:,h_src,:) plane) ----
    int soff[8];
    #pragma unroll
    for (int i = 0; i < 8; ++i) {
        const int c    = wv * 8 + i;             // chunk id (wave-uniform)
        const int p_f  = c * 256 + lane * 4;     // LDS float index this lane fills
        const int ch2  = p_f >> 5;               // half*128 + ch
        const int half = ch2 >> 7;
        const int ch   = ch2 & 127;
        const int qp   = (p_f >> 2) & 7;         // quad position in padded row
        int q = qp ^ ((ch >> 2) & 7);            // global quad this position holds
        q = q > 6 ? 6 : q;                       // pad slot: harmless dup (never read)
        soff[i] = (ch + (half << 7)) * 784 + q * 4;
    }

    // ---- prologue: issue DMA for row 0 ----
    {
        const int R = row0;
        const float* base = x + (size_t)(R / 28) * 200704 + ((R % 28 + 27) % 28) * 28;
        #pragma unroll
        for (int i = 0; i < 8; ++i)
            __builtin_amdgcn_global_load_lds(
                (const __attribute__((address_space(1))) void*)(base + soff[i]),
                (__attribute__((address_space(3))) void*)&raw[(wv * 8 + i) * 256],
                16, 0, 0);
    }

    // ---- per-thread weights (overlap DMA): thread t owns c = t = j*8+k ----
    const int j = t >> 3;
    const int k = t & 7;
    float wr[3][4][3];
    {
        const float* wp = Wt + j * 288 + k;      // W[j,a,m,b,k] strides 288/96/24/8/1
        #pragma unroll
        for (int a = 0; a < 3; ++a)
            #pragma unroll
            for (int m = 0; m < 4; ++m)
                #pragma unroll
                for (int bb = 0; bb < 3; ++bb)
                    wr[a][m][bb] = wp[a * 96 + m * 24 + bb * 8];
    }
    if (j == 0) {
        #pragma unroll
        for (int m = 0; m < 4; ++m)
            #pragma unroll
            for (int bb = 0; bb < 3; ++bb) wr[0][m][bb] = 0.f;
    }
    if (j == 31) {
        #pragma unroll
        for (int m = 0; m < 4; ++m)
            #pragma unroll
            for (int bb = 0; bb < 3; ++bb) wr[2][m][bb] = 0.f;
    }

    for (int r = 0; r < nrows; ++r) {
        const int R = row0 + r;
        const int n = R / 28;
        const int h = R - n * 28;

        // -- wait for row r's DMA (oldest 8 vmem ops); prev row's 7 stores may stay in flight --
        if (r == 0) asm volatile("s_waitcnt vmcnt(0)" ::: "memory");
        else        asm volatile("s_waitcnt vmcnt(7)" ::: "memory");
        __builtin_amdgcn_s_barrier();

        // -- reduce: sum = lo + hi (linear, conflict-free) --
        {
            const f32x4* r4 = (const f32x4*)raw;
            f32x4* s4 = (f32x4*)sum;
            #pragma unroll
            for (int i = 0; i < 4; ++i) {
                const int Q = t + i * 256;
                s4[Q] = r4[Q] + r4[Q + 1024];
            }
        }
        asm volatile("s_waitcnt lgkmcnt(0)" ::: "memory");
        __builtin_amdgcn_s_barrier();

        // -- issue DMA for row r+1 into raw (now safe: all waves done reading raw) --
        if (r + 1 < nrows) {
            const int Rn = R + 1;
            const float* base = x + (size_t)(Rn / 28) * 200704 + ((Rn % 28 + 27) % 28) * 28;
            #pragma unroll
            for (int i = 0; i < 8; ++i)
                __builtin_amdgcn_global_load_lds(
                    (const __attribute__((address_space(1))) void*)(base + soff[i]),
                    (__attribute__((address_space(3))) void*)&raw[(wv * 8 + i) * 256],
                    16, 0, 0);
        }

        // -- compute row r from sum --
        float acc[28];
        #pragma unroll
        for (int w = 0; w < 28; ++w) acc[w] = 0.f;

        #pragma unroll
        for (int a = 0; a < 3; ++a) {
            int g = j + a - 1;
            g = g < 0 ? 0 : (g > 31 ? 31 : g);   // weights already zeroed for OOB
            const int s = g & 7;
            #pragma unroll
            for (int m = 0; m < 4; ++m) {
                const int rowf = (g * 4 + m) * 32;
                const float w2 = wr[a][m][2];
                const float w1 = wr[a][m][1];
                const float w0 = wr[a][m][0];
                #pragma unroll
                for (int q = 0; q < 7; ++q) {
                    const f32x4 v = *(const f32x4*)&sum[rowf + ((q ^ s) << 2)];
                    #pragma unroll
                    for (int e = 0; e < 4; ++e) {
                        const int wp_ = q * 4 + e;                          // source col w'
                        if (wp_ != 27) acc[wp_] += v[e] * w2;               // b=2 tap
                        acc[(wp_ + 1) % 28] += v[e] * w1;                   // b=1 tap
                        if (wp_ != 26) acc[(wp_ + 2) % 28] += v[e] * w0;    // b=0 tap
                    }
                }
            }
        }

        // -- write OUT[n, t, h, 0..27]: 7 aligned float4 stores --
        float* op = out + (size_t)n * 200704 + (size_t)t * 784 + (size_t)h * 28;
        #pragma unroll
        for (int qq = 0; qq < 7; ++qq) {
            f32x4 o;
            o.x = acc[qq * 4 + 0];
            o.y = acc[qq * 4 + 1];
            o.z = acc[qq * 4 + 2];
            o.w = acc[qq * 4 + 3];
            *(f32x4*)(op + qq * 4) = o;
        }
    }
}

extern "C" void kernel_launch(void* const* d_in, const int* in_sizes, int n_in,
                              void* d_out, int out_size, void* d_ws, size_t ws_size,
                              hipStream_t stream) {
    const float* x  = (const float*)d_in[0];   // (128,256,28,28) f32
    const float* Wt = (const float*)d_in[1];   // (32,3,4,3,8)   f32
    float* out      = (float*)d_out;           // (128,256,28,28) f32

    fused_shift_conv<<<768, 256, 0, stream>>>(x, Wt, out);
}

// Round 6
// 72.893 us; speedup vs baseline: 6.2464x; 6.2464x over previous
//
#include <hip/hip_runtime.h>

typedef float __attribute__((ext_vector_type(4))) f32x4;

// OUT[n, c=j*8+k, h, w] = sum_{a,m,b} W[j,a,m,b,k] * T[n,(j+a-1)*4+m, (h-1)%28, (w+b-2)%28]
//   T[n,cc,h,w] = x[n,cc,h,w] + x[n,cc+128,h,w]
//   (j+a-1) outside [0,32) -> zero (channel pad); (w+b-1) outside [0,28) -> zero (w pad)
//
// R6 = R5 with the sync race fixed. Straight-line 2 rows/block (runtime loops around the
//   unrolled body caused scratch spill storms in R3/R4; counted vmcnt(7) raced in R5 because
//   the compiler may interleave output stores among the DMA issues). Here every wait is a
//   full vmcnt(0) drain -> no vmem-ordering assumptions. Stores are issued ~1300 cycles
//   before the drain, so their residual cost is tiny.
// Pipeline: DMA1 is issued right after raw becomes dead (post-reduce barrier), so its HBM
//   latency hides under row 0's 1008-FMA compute.
// LDS: raw 32 KB (DMA dest, linear) + sum 16 KB = 48 KB -> 3 blocks/CU. grid = 1792.
// Swizzle (R2-verified, 0 bank conflicts): quad pos qp = q ^ ((ch>>2)&7) applied to the
//   GLOBAL source address; pad slot duplicates quad 6, never read by compute.

__device__ __forceinline__ void issue_dma(const float* base, const int* soff,
                                          float* raw, int wv) {
    #pragma unroll
    for (int i = 0; i < 8; ++i)
        __builtin_amdgcn_global_load_lds(
            (const __attribute__((address_space(1))) void*)(base + soff[i]),
            (__attribute__((address_space(3))) void*)&raw[(wv * 8 + i) * 256],
            16, 0, 0);
}

__device__ __forceinline__ void reduce_halves(const float* raw, float* sum, int t) {
    const f32x4* r4 = (const f32x4*)raw;
    f32x4* s4 = (f32x4*)sum;
    #pragma unroll
    for (int i = 0; i < 4; ++i) {
        const int Q = t + i * 256;
        s4[Q] = r4[Q] + r4[Q + 1024];
    }
}

__device__ __forceinline__ void compute_store(const float* sum, const float (*wr)[4][3],
                                              int j, int t, float* op) {
    float acc[28];
    #pragma unroll
    for (int w = 0; w < 28; ++w) acc[w] = 0.f;

    #pragma unroll
    for (int a = 0; a < 3; ++a) {
        int g = j + a - 1;
        g = g < 0 ? 0 : (g > 31 ? 31 : g);       // weights already zeroed for OOB
        const int s = g & 7;
        #pragma unroll
        for (int m = 0; m < 4; ++m) {
            const int rowf = (g * 4 + m) * 32;
            const float w2 = wr[a][m][2];
            const float w1 = wr[a][m][1];
            const float w0 = wr[a][m][0];
            #pragma unroll
            for (int q = 0; q < 7; ++q) {
                const f32x4 v = *(const f32x4*)&sum[rowf + ((q ^ s) << 2)];
                #pragma unroll
                for (int e = 0; e < 4; ++e) {
                    const int wp_ = q * 4 + e;                          // source col w'
                    if (wp_ != 27) acc[wp_] += v[e] * w2;               // b=2 tap
                    acc[(wp_ + 1) % 28] += v[e] * w1;                   // b=1 tap
                    if (wp_ != 26) acc[(wp_ + 2) % 28] += v[e] * w0;    // b=0 tap
                }
            }
        }
    }

    #pragma unroll
    for (int qq = 0; qq < 7; ++qq) {
        f32x4 o;
        o.x = acc[qq * 4 + 0];
        o.y = acc[qq * 4 + 1];
        o.z = acc[qq * 4 + 2];
        o.w = acc[qq * 4 + 3];
        *(f32x4*)(op + qq * 4) = o;
    }
}

__global__ __launch_bounds__(256) void fused_shift_conv(
    const float* __restrict__ x, const float* __restrict__ Wt, float* __restrict__ out)
{
    __shared__ __align__(16) float raw[8192];   // [half][ch][32] quad-swizzled, 32 KB
    __shared__ __align__(16) float sum[4096];   // [ch][32] reduced, 16 KB

    const int R0 = blockIdx.x * 2;              // global output row index n*28+h
    const int R1 = R0 + 1;
    const int n0 = R0 / 28, h0 = R0 - n0 * 28;
    const int n1 = R1 / 28, h1 = R1 - n1 * 28;

    const int t    = threadIdx.x;
    const int lane = t & 63;
    const int wv   = t >> 6;

    // ---- row-invariant DMA source offsets (within one (n,:,h_src,:) plane) ----
    int soff[8];
    #pragma unroll
    for (int i = 0; i < 8; ++i) {
        const int c    = wv * 8 + i;             // chunk id (wave-uniform)
        const int p_f  = c * 256 + lane * 4;     // LDS float index this lane fills
        const int ch2  = p_f >> 5;               // half*128 + ch
        const int half = ch2 >> 7;
        const int ch   = ch2 & 127;
        const int qp   = (p_f >> 2) & 7;         // quad position in padded row
        int q = qp ^ ((ch >> 2) & 7);            // global quad this position holds
        q = q > 6 ? 6 : q;                       // pad slot: harmless dup (never read)
        soff[i] = (ch + (half << 7)) * 784 + q * 4;
    }

    // ---- issue DMA for row 0 ----
    issue_dma(x + (size_t)n0 * 200704 + ((h0 + 27) % 28) * 28, soff, raw, wv);

    // ---- per-thread weights (loads overlap DMA): thread t owns c = t = j*8+k ----
    const int j = t >> 3;
    const int k = t & 7;
    float wr[3][4][3];
    {
        const float* wp = Wt + j * 288 + k;      // W[j,a,m,b,k] strides 288/96/24/8/1
        #pragma unroll
        for (int a = 0; a < 3; ++a)
            #pragma unroll
            for (int m = 0; m < 4; ++m)
                #pragma unroll
                for (int bb = 0; bb < 3; ++bb)
                    wr[a][m][bb] = wp[a * 96 + m * 24 + bb * 8];
    }
    if (j == 0) {
        #pragma unroll
        for (int m = 0; m < 4; ++m)
            #pragma unroll
            for (int bb = 0; bb < 3; ++bb) wr[0][m][bb] = 0.f;
    }
    if (j == 31) {
        #pragma unroll
        for (int m = 0; m < 4; ++m)
            #pragma unroll
            for (int bb = 0; bb < 3; ++bb) wr[2][m][bb] = 0.f;
    }

    // ---- row 0 ----
    asm volatile("s_waitcnt vmcnt(0)" ::: "memory");   // DMA0 (and weight loads) done
    __builtin_amdgcn_s_barrier();

    reduce_halves(raw, sum, t);
    asm volatile("s_waitcnt lgkmcnt(0)" ::: "memory");
    __builtin_amdgcn_s_barrier();                      // all waves done with raw

    // raw is dead: issue DMA for row 1; its latency hides under compute0
    issue_dma(x + (size_t)n1 * 200704 + ((h1 + 27) % 28) * 28, soff, raw, wv);
    __builtin_amdgcn_sched_barrier(0);                 // keep DMA issues ahead of compute

    compute_store(sum, wr, j, t,
                  out + (size_t)n0 * 200704 + (size_t)t * 784 + (size_t)h0 * 28);

    // ---- row 1 ----
    asm volatile("s_waitcnt vmcnt(0)" ::: "memory");   // full drain: DMA1 + store0 (retired)
    __builtin_amdgcn_s_barrier();                      // also: all waves done reading sum

    reduce_halves(raw, sum, t);
    asm volatile("s_waitcnt lgkmcnt(0)" ::: "memory");
    __builtin_amdgcn_s_barrier();

    compute_store(sum, wr, j, t,
                  out + (size_t)n1 * 200704 + (size_t)t * 784 + (size_t)h1 * 28);
}

extern "C" void kernel_launch(void* const* d_in, const int* in_sizes, int n_in,
                              void* d_out, int out_size, void* d_ws, size_t ws_size,
                              hipStream_t stream) {
    const float* x  = (const float*)d_in[0];   // (128,256,28,28) f32
    const float* Wt = (const float*)d_in[1];   // (32,3,4,3,8)   f32
    float* out      = (float*)d_out;           // (128,256,28,28) f32

    fused_shift_conv<<<1792, 256, 0, stream>>>(x, Wt, out);
}

// Round 7
// 68.445 us; speedup vs baseline: 6.6523x; 1.0650x over previous
//
#include <hip/hip_runtime.h>

typedef float __attribute__((ext_vector_type(4))) f32x4;
typedef unsigned int u32;
typedef u32 __attribute__((ext_vector_type(4))) u32x4;

// OUT[n, c=j*8+k, h, w] = sum_{a,m,b} W[j,a,m,b,k] * T[n,(j+a-1)*4+m, (h-1)%28, (w+b-2)%28]
//   T[n,cc,h,w] = x[n,cc,h,w] + x[n,cc+128,h,w]
//   (j+a-1) outside [0,32) -> zero (channel pad); (w+b-1) outside [0,28) -> zero (w pad)
//
// R7: bf16-pair LDS + v_dot2_f32_bf16 (f32 accumulate). T packed along m: LDS row
//   rr = g*2+mp holds dwords (bf16(T[4g+2mp, w']), bf16(T[4g+2mp+1, w'])) for w'=0..27,
//   pitch 32 dwords. One ds_read_b128 = 8 T values; one dot2 = 2 MACs.
//   Per thread-row: 42 ds_read_b128 (was 84) + 504 dot2 (was 1008 FMA). LDS = 8 KB.
// Swizzle (R2-proven): dword-quad slot = qb ^ (g&7); a wave's 8 j-groups hit 8 distinct
//   slots -> all 32 banks -> conflict-free compute reads. Slot 7^g = pad, never read.
// Staging: reg-staged (8x global_load_dwordx4, sum halves in reg, RNE-pack to bf16,
//   2x ds_write_b128). No DMA, no reduce phase, 1 barrier, one row per block.

__device__ __forceinline__ u32 pack2bf(float lo, float hi) {
    u32 a = __float_as_uint(lo), b = __float_as_uint(hi);
    a = (a + 0x7FFFu + ((a >> 16) & 1u)) >> 16;   // RNE round to bf16
    b = (b + 0x7FFFu + ((b >> 16) & 1u)) >> 16;
    return a | (b << 16);
}

__device__ __forceinline__ float dot2bf(u32 t2, u32 w2, float acc) {
    asm("v_dot2_f32_bf16 %0, %1, %2, %0" : "+v"(acc) : "v"(t2), "v"(w2));
    return acc;
}

__global__ __launch_bounds__(256, 4) void fused_shift_conv(
    const float* __restrict__ x, const float* __restrict__ Wt, float* __restrict__ out)
{
    __shared__ __align__(16) u32 B[2048];   // 64 rows x 32 dwords = 8 KB

    const int R = blockIdx.x;               // global row index n*28 + h
    const int n = R / 28;
    const int h = R - n * 28;
    const int h_src = (h + 27) % 28;        // roll(+1) along h

    const int t = threadIdx.x;

    // ---- staging: thread t fills row rr = t>>2 (ch pair 4g+2mp, +1), quads qA,qA+1 ----
    const int rr = t >> 2;                  // 0..63
    const int gs = rr >> 1;                 // group 0..31
    const int mp = rr & 1;                  // m-pair 0/1
    const int ch0 = gs * 4 + mp * 2;
    const int qA  = (t & 3) * 2;            // 0,2,4,6
    const int qBr = qA + 1;                 // 1,3,5,7
    const int qB  = (qBr > 6) ? 6 : qBr;    // clamp: pad slot gets dup of quad 6
    const int sw  = gs & 7;
    const int dA  = rr * 32 + (qA ^ sw) * 4;   // dword index of b128 write A
    const int dB  = rr * 32 + (qBr ^ sw) * 4;  // pad slot (7^sw) never read

    const float* base = x + (size_t)n * 200704 + h_src * 28;
    const float* pA = base + ch0 * 784 + qA * 4;
    const float* pB = base + ch0 * 784 + qB * 4;

    const f32x4 l0A = *(const f32x4*)pA;
    const f32x4 h0A = *(const f32x4*)(pA + 100352);
    const f32x4 l1A = *(const f32x4*)(pA + 784);
    const f32x4 h1A = *(const f32x4*)(pA + 784 + 100352);
    const f32x4 l0B = *(const f32x4*)pB;
    const f32x4 h0B = *(const f32x4*)(pB + 100352);
    const f32x4 l1B = *(const f32x4*)(pB + 784);
    const f32x4 h1B = *(const f32x4*)(pB + 784 + 100352);

    const f32x4 s0A = l0A + h0A, s1A = l1A + h1A;
    const f32x4 s0B = l0B + h0B, s1B = l1B + h1B;
    u32x4 wvA, wvB;
    #pragma unroll
    for (int e = 0; e < 4; ++e) {
        wvA[e] = pack2bf(s0A[e], s1A[e]);   // low = ch 4g+2mp, high = ch 4g+2mp+1
        wvB[e] = pack2bf(s0B[e], s1B[e]);
    }
    *(u32x4*)&B[dA] = wvA;
    *(u32x4*)&B[dB] = wvB;

    // ---- per-thread weights, bf16-pair packed along m: thread t owns c = j*8+k ----
    const int j = t >> 3, k = t & 7;
    u32 w2[3][2][3];                        // [a][m-pair][tap]
    {
        const float* wp = Wt + j * 288 + k; // W[j,a,m,b,k] strides 288/96/24/8/1
        #pragma unroll
        for (int a = 0; a < 3; ++a)
            #pragma unroll
            for (int m2 = 0; m2 < 2; ++m2)
                #pragma unroll
                for (int bb = 0; bb < 3; ++bb)
                    w2[a][m2][bb] = pack2bf(wp[a*96 + (2*m2  )*24 + bb*8],
                                            wp[a*96 + (2*m2+1)*24 + bb*8]);
    }
    if (j == 0) {
        #pragma unroll
        for (int m2 = 0; m2 < 2; ++m2)
            #pragma unroll
            for (int bb = 0; bb < 3; ++bb) w2[0][m2][bb] = 0u;
    }
    if (j == 31) {
        #pragma unroll
        for (int m2 = 0; m2 < 2; ++m2)
            #pragma unroll
            for (int bb = 0; bb < 3; ++bb) w2[2][m2][bb] = 0u;
    }

    __syncthreads();

    // ---- compute: 42 ds_read_b128 + ~492 v_dot2_f32_bf16 ----
    float acc[28];
    #pragma unroll
    for (int w = 0; w < 28; ++w) acc[w] = 0.f;

    #pragma unroll
    for (int a = 0; a < 3; ++a) {
        int g = j + a - 1;
        g = g < 0 ? 0 : (g > 31 ? 31 : g);  // weights already zeroed for OOB
        const int s = g & 7;
        #pragma unroll
        for (int m2 = 0; m2 < 2; ++m2) {
            const int rowd = (g * 2 + m2) * 32;
            const u32 t2 = w2[a][m2][2], t1 = w2[a][m2][1], t0 = w2[a][m2][0];
            #pragma unroll
            for (int qb = 0; qb < 7; ++qb) {
                const u32x4 v = *(const u32x4*)&B[rowd + ((qb ^ s) << 2)];
                #pragma unroll
                for (int e = 0; e < 4; ++e) {
                    const int wp_ = qb * 4 + e;                              // source col w'
                    if (wp_ != 27) acc[wp_] = dot2bf(v[e], t2, acc[wp_]);    // b=2 tap
                    acc[(wp_ + 1) % 28] = dot2bf(v[e], t1, acc[(wp_ + 1) % 28]); // b=1
                    if (wp_ != 26) acc[(wp_ + 2) % 28] = dot2bf(v[e], t0, acc[(wp_ + 2) % 28]); // b=0
                }
            }
        }
    }

    // ---- write OUT[n, t, h, 0..27]: 7 aligned float4 stores ----
    float* op = out + (size_t)n * 200704 + (size_t)t * 784 + (size_t)h * 28;
    #pragma unroll
    for (int qq = 0; qq < 7; ++qq) {
        f32x4 o;
        o.x = acc[qq * 4 + 0];
        o.y = acc[qq * 4 + 1];
        o.z = acc[qq * 4 + 2];
        o.w = acc[qq * 4 + 3];
        *(f32x4*)(op + qq * 4) = o;
    }
}

extern "C" void kernel_launch(void* const* d_in, const int* in_sizes, int n_in,
                              void* d_out, int out_size, void* d_ws, size_t ws_size,
                              hipStream_t stream) {
    const float* x  = (const float*)d_in[0];   // (128,256,28,28) f32
    const float* Wt = (const float*)d_in[1];   // (32,3,4,3,8)   f32
    float* out      = (float*)d_out;           // (128,256,28,28) f32

    const int nbatch = in_sizes[0] / 200704;   // 128
    fused_shift_conv<<<nbatch * 28, 256, 0, stream>>>(x, Wt, out);
}